// Round 1
// baseline (116.448 us; speedup 1.0000x reference)
//
#include <hip/hip_runtime.h>

// B=32, S=4096, C=64, D=2. x:[B,S,C,D] fp32, W_nonlin/W_coeff:[C,2,2] fp32.
// Per site: y = Wn @ x (2x2), amp = |y|^2, c = amp*y, z = Wc @ c.
// Memory-bound: 64 MiB in + 64 MiB out. One thread per float4 (2 channel pairs).
// Channel-pair index = float4_idx % 32 is grid-stride-invariant (stride % 32 == 0),
// so weights live in 16 registers, loaded once per thread.

__global__ __launch_bounds__(256) void fused_cplx_nonlin_kernel(
    const float4* __restrict__ x,
    const float4* __restrict__ Wn,   // [C,2,2] viewed as float4[C]: {w00,w01,w10,w11}
    const float4* __restrict__ Wc,
    float4* __restrict__ z,
    int n4, int stride)
{
    const int g  = blockIdx.x * 256 + threadIdx.x;
    const int cp = g & 31;           // channel-pair (channels 2cp, 2cp+1)

    // Hoist weights for both channels into registers (one-time, cache-broadcast).
    const float4 wn0 = Wn[2 * cp];
    const float4 wn1 = Wn[2 * cp + 1];
    const float4 wc0 = Wc[2 * cp];
    const float4 wc1 = Wc[2 * cp + 1];

    for (int idx = g; idx < n4; idx += stride) {
        const float4 v = x[idx];
        float4 r;

        // channel 2cp: input (v.x, v.y)
        {
            float y0  = v.x * wn0.x + v.y * wn0.y;
            float y1  = v.x * wn0.z + v.y * wn0.w;
            float amp = y0 * y0 + y1 * y1;
            float c0  = amp * y0;
            float c1  = amp * y1;
            r.x = c0 * wc0.x + c1 * wc0.y;
            r.y = c0 * wc0.z + c1 * wc0.w;
        }
        // channel 2cp+1: input (v.z, v.w)
        {
            float y0  = v.z * wn1.x + v.w * wn1.y;
            float y1  = v.z * wn1.z + v.w * wn1.w;
            float amp = y0 * y0 + y1 * y1;
            float c0  = amp * y0;
            float c1  = amp * y1;
            r.z = c0 * wc1.x + c1 * wc1.y;
            r.w = c0 * wc1.z + c1 * wc1.w;
        }

        z[idx] = r;
    }
}

extern "C" void kernel_launch(void* const* d_in, const int* in_sizes, int n_in,
                              void* d_out, int out_size, void* d_ws, size_t ws_size,
                              hipStream_t stream) {
    const float4* x  = (const float4*)d_in[0];
    const float4* Wn = (const float4*)d_in[1];
    const float4* Wc = (const float4*)d_in[2];
    float4* z        = (float4*)d_out;

    const int n4     = in_sizes[0] / 4;   // 4,194,304 float4s
    const int blocks = 2048;              // 8 blocks/CU * 256 CUs -> full occupancy
    const int stride = blocks * 256;      // multiple of 32: channel invariant

    fused_cplx_nonlin_kernel<<<blocks, 256, 0, stream>>>(x, Wn, Wc, z, n4, stride);
}